// Round 17
// baseline (661.021 us; speedup 1.0000x reference)
//
#include <hip/hip_runtime.h>
#include <hip/hip_bf16.h>
#include <math.h>

typedef short bf16x8 __attribute__((ext_vector_type(8)));
typedef float f32x4 __attribute__((ext_vector_type(4)));
typedef unsigned int u32;
typedef unsigned short u16;

#define NROWS 131072
#define DDIM 224
#define HREAL 400
#define HP 416          // padded hidden dim (13*32)
#define ROWS 32         // rows per tile
#define NTILES 4096     // 4096 tiles of 32 rows = 131072 rows (both paths)
#define PROW 832        // bytes per plane row (416 * 2B = 52 units of 16B)
#define PLANE 26624     // one plane: [32][416] bf16
#define LDS_TOTAL 53248 // plane A + plane B; 3 blocks/CU
#define SPLIT_TILES 4096
#define SPLIT_GRID 768

// ---- workspace layout (bytes); weights interleaved hi|lo per fragment ----
#define OFF_W1    0          // [26nb][7ks][4g][16l][8hi|8lo] u16 = 372736 B
#define OFF_W2    372736     // [26][13][4][16][16] = 692224 B
#define OFF_W5    1064960    // 692224 B
#define OFF_W6    1757184    // [14][13][4][16][16] = 372736 B
#define OFF_C     2129920    // f32 scalar ||d||
#define OFF_MSEP  2129936    // f32 [4096]
#define OFF_DEFEN 2146320    // f32 [131072]
#define OFF_CAND  2670608    // f32 [1280]
#define OFF_WE3T  2675728    // f32 [4][416]
#define OFF_P0    2682880    // bf16 planes, 4096 * 26624
#define PBYTES    109051904ull
#define OFF_P1    (OFF_P0 + PBYTES)
#define WS_NEED   (OFF_P1 + PBYTES)

__device__ __forceinline__ u16 f2bf(float v) {
  union { float f; u32 u; } a; a.f = v;
  u32 u = a.u;
  u += 0x7fffu + ((u >> 16) & 1u);
  return (u16)(u >> 16);
}
__device__ __forceinline__ float bf2f(u16 h) {
  union { u32 u; float f; } a; a.u = ((u32)h) << 16; return a.f;
}
__device__ __forceinline__ int rotu(int r, int u) {
  int s = u + r;
  if (s >= 52) s -= 52;
  if (s >= 52) s -= 52;
  return s;
}

__device__ __forceinline__ void pack16(int i, int NKS, int KREAL, int NREAL, int NLD,
                                       const float* __restrict__ W,
                                       u16* __restrict__ Wo) {
  const int e = i & 7, half = (i >> 3) & 1;
  const int l15 = (i >> 4) & 15, g = (i >> 8) & 3;
  const int rest = i >> 10;
  const int ks = rest % NKS, nb = rest / NKS;
  const int n = nb * 16 + l15, k = ks * 32 + g * 8 + e;
  const float w = (n < NREAL && k < KREAL) ? W[k * NLD + n] : 0.f;
  const u16 h = f2bf(w);
  Wo[i] = half ? f2bf(w - bf2f(h)) : h;
}

__global__ void k_prep(const float* __restrict__ We1, const float* __restrict__ We2,
                       const float* __restrict__ Wd2, const float* __restrict__ Wd3,
                       const float* __restrict__ We3, const float* __restrict__ dvec,
                       u16* __restrict__ W1, u16* __restrict__ W2,
                       u16* __restrict__ W5, u16* __restrict__ W6,
                       float* __restrict__ We3T, float* __restrict__ Cout) {
  const int t = blockIdx.x * 256 + threadIdx.x;
  const int NT = gridDim.x * 256;
  for (int i = t; i < 26 * 7 * 1024;  i += NT) pack16(i, 7,  DDIM,  HREAL, HREAL, We1, W1);
  for (int i = t; i < 26 * 13 * 1024; i += NT) pack16(i, 13, HREAL, HREAL, HREAL, We2, W2);
  for (int i = t; i < 26 * 13 * 1024; i += NT) pack16(i, 13, HREAL, HREAL, HREAL, Wd2, W5);
  for (int i = t; i < 14 * 13 * 1024; i += NT) pack16(i, 13, HREAL, DDIM,  DDIM,  Wd3, W6);
  for (int i = t; i < 4 * 416; i += NT) {
    const int j = i / 416, k = i - j * 416;
    We3T[i] = (k < HREAL) ? We3[k * 4 + j] : 0.f;
  }
  if (blockIdx.x == 0) {
    float s = 0.f;
    for (int i = threadIdx.x; i < DDIM; i += 256) { float v = dvec[i]; s += v * v; }
#pragma unroll
    for (int off = 1; off < 64; off <<= 1) s += __shfl_xor(s, off);
    __shared__ float cs[4];
    if ((threadIdx.x & 63) == 0) cs[threadIdx.x >> 6] = s;
    __syncthreads();
    if (threadIdx.x == 0) Cout[0] = sqrtf(cs[0] + cs[1] + cs[2] + cs[3]);
  }
}

// ------- GEMM chunk: 2 M-frags x 2 N-frags, 1-k-step-deep weight prefetch (R14) -------
template <int NKS>
__device__ __forceinline__ void gemm2(const char* ip, const u16* __restrict__ W,
                                      int nb0, int l15, int g, f32x4 (&acc)[2][2]) {
  const int lof = (g << 8) + (l15 << 4);
  const u16* w0 = W + ((((size_t)nb0 * NKS) << 10) + lof);
  const u16* w1 = W + ((((size_t)(nb0 + 1) * NKS) << 10) + lof);
  bf16x8 c0h = *(const bf16x8*)w0;
  bf16x8 c0l = *(const bf16x8*)(w0 + 8);
  bf16x8 c1h = *(const bf16x8*)w1;
  bf16x8 c1l = *(const bf16x8*)(w1 + 8);
#pragma unroll
  for (int ks = 0; ks < NKS; ++ks) {
    int s0 = ks * 4 + g + l15;
    if (s0 >= 52) s0 -= 52;
    int s1 = s0 + 16;
    if (s1 >= 52) s1 -= 52;
    const bf16x8 a0 = *(const bf16x8*)(ip + l15 * PROW + s0 * 16);
    const bf16x8 a1 = *(const bf16x8*)(ip + (l15 + 16) * PROW + s1 * 16);
    bf16x8 n0h, n0l, n1h, n1l;
    if (ks + 1 < NKS) {
      const u16* p0 = w0 + (size_t)(ks + 1) * 1024;
      const u16* p1 = w1 + (size_t)(ks + 1) * 1024;
      n0h = *(const bf16x8*)p0;
      n0l = *(const bf16x8*)(p0 + 8);
      n1h = *(const bf16x8*)p1;
      n1l = *(const bf16x8*)(p1 + 8);
    }
    __builtin_amdgcn_s_setprio(1);
    acc[0][0] = __builtin_amdgcn_mfma_f32_16x16x32_bf16(a0, c0h, acc[0][0], 0, 0, 0);
    acc[0][0] = __builtin_amdgcn_mfma_f32_16x16x32_bf16(a0, c0l, acc[0][0], 0, 0, 0);
    acc[1][0] = __builtin_amdgcn_mfma_f32_16x16x32_bf16(a1, c0h, acc[1][0], 0, 0, 0);
    acc[1][0] = __builtin_amdgcn_mfma_f32_16x16x32_bf16(a1, c0l, acc[1][0], 0, 0, 0);
    acc[0][1] = __builtin_amdgcn_mfma_f32_16x16x32_bf16(a0, c1h, acc[0][1], 0, 0, 0);
    acc[0][1] = __builtin_amdgcn_mfma_f32_16x16x32_bf16(a0, c1l, acc[0][1], 0, 0, 0);
    acc[1][1] = __builtin_amdgcn_mfma_f32_16x16x32_bf16(a1, c1h, acc[1][1], 0, 0, 0);
    acc[1][1] = __builtin_amdgcn_mfma_f32_16x16x32_bf16(a1, c1l, acc[1][1], 0, 0, 0);
    __builtin_amdgcn_s_setprio(0);
    if (ks + 1 < NKS) { c0h = n0h; c0l = n0l; c1h = n1h; c1l = n1l; }
  }
}

__device__ __forceinline__ void epi2(f32x4 (&acc)[2][2], const float* __restrict__ bias,
                                     int nb0, char* op, int l15, int g) {
#pragma unroll
  for (int nf = 0; nf < 2; ++nf) {
    const int col = (nb0 + nf) * 16 + l15;
    const float bv = (col < HREAL) ? bias[col] : 0.f;
    const int cu = col >> 3;
    const int crem = (col & 7) * 2;
#pragma unroll
    for (int mf = 0; mf < 2; ++mf) {
#pragma unroll
      for (int j = 0; j < 4; ++j) {
        const int row = mf * 16 + g * 4 + j;
        float v = acc[mf][nf][j] + bv;
        v = fmaxf(v, 0.1f * v);
        *(u16*)(op + row * PROW + rotu(row, cu) * 16 + crem) = f2bf(v);
      }
    }
  }
}

// ---- helpers: stage x tile -> plane (convert), linear plane copies ----
__device__ __forceinline__ void stage_x(const float* __restrict__ xin, size_t row0,
                                        char* pl, int tid) {
#pragma unroll
  for (int i = 0; i < 7; ++i) {
    const int f = i * 256 + tid;
    const int r = f / 56, c4 = f - r * 56;
    const float4 v = *(const float4*)(xin + (row0 + r) * DDIM + c4 * 4);
    const float vv[4] = {v.x, v.y, v.z, v.w};
    ushort4 hh;
    u16* hw = (u16*)&hh;
#pragma unroll
    for (int w = 0; w < 4; ++w) hw[w] = f2bf(vv[w]);
    *(ushort4*)(pl + r * PROW + rotu(r, c4 >> 1) * 16 + (c4 & 1) * 8) = hh;
  }
}
__device__ __forceinline__ void copy_in(const char* __restrict__ gp, char* pl, int tid) {
#pragma unroll
  for (int i = 0; i < 7; ++i) {
    const int idx = i * 256 + tid;
    if (idx < 1664) ((uint4*)pl)[idx] = ((const uint4*)gp)[idx];
  }
}
__device__ __forceinline__ void copy_out(const char* pl, char* __restrict__ gp, int tid) {
#pragma unroll
  for (int i = 0; i < 7; ++i) {
    const int idx = i * 256 + tid;
    if (idx < 1664) ((uint4*)gp)[idx] = ((const uint4*)pl)[idx];
  }
}

// ---- L3/L4 body (shared): reads in-plane, writes g1 to out-plane + z_out ----
__device__ __forceinline__ void l34_body(const char* pa, char* pb,
    const float* __restrict__ We3T, const float* __restrict__ be3,
    const float* __restrict__ Wd1, const float* __restrict__ bd1,
    float* __restrict__ z_out, size_t row0, int tid, int lane) {
  float zval;
  {
    const int r = tid >> 3;
    const int t8 = tid & 7;
    const int j = t8 & 3, half = t8 >> 2;
    const char* hb = pa + r * PROW;
    const float* wrow = We3T + j * 416;
    float s0 = 0.f, s1 = 0.f;
#pragma unroll 2
    for (int it = 0; it < 25; ++it) {
      const int k = half * 200 + it * 8;
      const bf16x8 h8 = *(const bf16x8*)(hb + rotu(r, half * 25 + it) * 16);
      const float4 w0 = *(const float4*)(wrow + k);
      const float4 w1 = *(const float4*)(wrow + k + 4);
      s0 = fmaf(bf2f((u16)h8[0]), w0.x, s0);
      s1 = fmaf(bf2f((u16)h8[1]), w0.y, s1);
      s0 = fmaf(bf2f((u16)h8[2]), w0.z, s0);
      s1 = fmaf(bf2f((u16)h8[3]), w0.w, s1);
      s0 = fmaf(bf2f((u16)h8[4]), w1.x, s0);
      s1 = fmaf(bf2f((u16)h8[5]), w1.y, s1);
      s0 = fmaf(bf2f((u16)h8[6]), w1.z, s0);
      s1 = fmaf(bf2f((u16)h8[7]), w1.w, s1);
    }
    float s = s0 + s1;
    s += __shfl_xor(s, 4);
    s += be3[j];
    zval = s;
    if (half == 0) z_out[(row0 + r) * 4 + j] = s;
  }
  {
    const int r = tid >> 3, q = tid & 7;
    float z[4];
#pragma unroll
    for (int jj = 0; jj < 4; ++jj) z[jj] = __shfl(zval, (lane & ~7) + jj);
#pragma unroll 2
    for (int u = 0; u < 13; ++u) {
      const int c4 = q * 13 + u;
      ushort4 hh;
      u16* hw = (u16*)&hh;
      if (c4 < 100) {
        const float4 w0 = *(const float4*)(Wd1 + 0 * HREAL + c4 * 4);
        const float4 w1 = *(const float4*)(Wd1 + 1 * HREAL + c4 * 4);
        const float4 w2 = *(const float4*)(Wd1 + 2 * HREAL + c4 * 4);
        const float4 w3 = *(const float4*)(Wd1 + 3 * HREAL + c4 * 4);
        const float4 bb = *(const float4*)(bd1 + c4 * 4);
        const float ww[4][4] = {{w0.x, w1.x, w2.x, w3.x}, {w0.y, w1.y, w2.y, w3.y},
                                {w0.z, w1.z, w2.z, w3.z}, {w0.w, w1.w, w2.w, w3.w}};
        const float bbv[4] = {bb.x, bb.y, bb.z, bb.w};
#pragma unroll
        for (int w = 0; w < 4; ++w) {
          float v = fmaf(z[0], ww[w][0], fmaf(z[1], ww[w][1],
                    fmaf(z[2], ww[w][2], fmaf(z[3], ww[w][3], bbv[w]))));
          v = fmaxf(v, 0.1f * v);
          hw[w] = f2bf(v);
        }
      } else {
        hw[0] = hw[1] = hw[2] = hw[3] = 0;
      }
      *(ushort4*)(pb + r * PROW + rotu(r, c4 >> 1) * 16 + (c4 & 1) * 8) = hh;
    }
  }
}

// ---- L6 body (shared): gemm+tanh+y+partials+reductions; M returned via msep slot ----
__device__ __forceinline__ void l6_body(const char* pa, char* pb,
    const u16* __restrict__ W6, const float* __restrict__ bd3,
    const float* __restrict__ dvec, const float* __restrict__ xin,
    const float* __restrict__ Cptr, float* __restrict__ y_out,
    float* __restrict__ defen, float* __restrict__ msep_slot,
    size_t row0, int tid, int wid, int l15, int g) {
  float pA[2][4] = {}, pB[2][4] = {}, pM[2][4] = {};
  for (int c = wid; c < 7; c += 4) {
    const int nb0 = 2 * c;
    f32x4 acc[2][2] = {};
    gemm2<13>(pa, W6, nb0, l15, g, acc);
#pragma unroll
    for (int mf = 0; mf < 2; ++mf) {
#pragma unroll
      for (int j = 0; j < 4; ++j) {
        const size_t grow = row0 + mf * 16 + g * 4 + j;
#pragma unroll
        for (int nf = 0; nf < 2; ++nf) {
          const int col = (nb0 + nf) * 16 + l15;
          const float v = acc[mf][nf][j] + bd3[col];
          const float e = __expf(2.f * v);
          const float y = 1.f - 2.f * __builtin_amdgcn_rcpf(e + 1.f);
          y_out[grow * DDIM + col] = y;
          pA[mf][j] = fmaf(y, dvec[col], pA[mf][j]);
          pB[mf][j] = fmaf(y, y, pB[mf][j]);
          const float df = y - xin[grow * DDIM + col];
          pM[mf][j] = fmaf(df, df, pM[mf][j]);
        }
      }
    }
  }
  float* red = (float*)pb;
#pragma unroll
  for (int mf = 0; mf < 2; ++mf) {
#pragma unroll
    for (int j = 0; j < 4; ++j) {
      float a = pA[mf][j], b = pB[mf][j], m = pM[mf][j];
#pragma unroll
      for (int off = 1; off < 16; off <<= 1) {
        a += __shfl_xor(a, off);
        b += __shfl_xor(b, off);
        m += __shfl_xor(m, off);
      }
      if (l15 == 0) {
        const int lrow = mf * 16 + g * 4 + j;
        red[(lrow * 4 + wid) * 4 + 0] = a;
        red[(lrow * 4 + wid) * 4 + 1] = b;
        red[(lrow * 4 + wid) * 4 + 2] = m;
      }
    }
  }
  __syncthreads();
  if (tid < 32) {
    const float Cn = Cptr[0];
    float A = 0.f, B2 = 0.f, M = 0.f;
#pragma unroll
    for (int w = 0; w < 4; ++w) {
      A  += red[(tid * 4 + w) * 4 + 0];
      B2 += red[(tid * 4 + w) * 4 + 1];
      M  += red[(tid * 4 + w) * 4 + 2];
    }
    defen[row0 + tid] = A / (sqrtf(B2) * Cn + 1e-5f);
#pragma unroll
    for (int off = 1; off < 32; off <<= 1) M += __shfl_xor(M, off);
    if (tid == 0) msep_slot[0] = M;
  }
}

// ================= split-path kernels (layer-major, grid-stride tiles) =================
__global__ __launch_bounds__(256, 3) void k_l1(
    const float* __restrict__ xin, const u16* __restrict__ W1,
    const float* __restrict__ be1, char* __restrict__ P0) {
  extern __shared__ __align__(16) char lds[];
  char* pa = lds;
  char* pb = lds + PLANE;
  const int tid = threadIdx.x;
  const int lane = tid & 63;
  const int wid = tid >> 6, l15 = lane & 15, g = lane >> 4;
  for (int t = blockIdx.x; t < SPLIT_TILES; t += gridDim.x) {
    stage_x(xin, (size_t)t * ROWS, pa, tid);
    __syncthreads();
    for (int c = wid; c < 13; c += 4) {
      f32x4 acc[2][2] = {};
      gemm2<7>(pa, W1, 2 * c, l15, g, acc);
      epi2(acc, be1, 2 * c, pb, l15, g);
    }
    __syncthreads();
    copy_out(pb, P0 + (size_t)t * PLANE, tid);
    __syncthreads();
  }
}

__global__ __launch_bounds__(256, 3) void k_gemm13(
    const char* __restrict__ Pin, const u16* __restrict__ W,
    const float* __restrict__ bias, char* __restrict__ Pout) {
  extern __shared__ __align__(16) char lds[];
  char* pa = lds;
  char* pb = lds + PLANE;
  const int tid = threadIdx.x;
  const int lane = tid & 63;
  const int wid = tid >> 6, l15 = lane & 15, g = lane >> 4;
  for (int t = blockIdx.x; t < SPLIT_TILES; t += gridDim.x) {
    copy_in(Pin + (size_t)t * PLANE, pa, tid);
    __syncthreads();
    for (int c = wid; c < 13; c += 4) {
      f32x4 acc[2][2] = {};
      gemm2<13>(pa, W, 2 * c, l15, g, acc);
      epi2(acc, bias, 2 * c, pb, l15, g);
    }
    __syncthreads();
    copy_out(pb, Pout + (size_t)t * PLANE, tid);
    __syncthreads();
  }
}

__global__ __launch_bounds__(256, 3) void k_l34(
    const char* __restrict__ Pin, char* __restrict__ Pout,
    const float* __restrict__ We3T, const float* __restrict__ be3,
    const float* __restrict__ Wd1, const float* __restrict__ bd1,
    float* __restrict__ z_out) {
  extern __shared__ __align__(16) char lds[];
  char* pa = lds;
  char* pb = lds + PLANE;
  const int tid = threadIdx.x;
  const int lane = tid & 63;
  for (int t = blockIdx.x; t < SPLIT_TILES; t += gridDim.x) {
    copy_in(Pin + (size_t)t * PLANE, pa, tid);
    __syncthreads();
    l34_body(pa, pb, We3T, be3, Wd1, bd1, z_out, (size_t)t * ROWS, tid, lane);
    __syncthreads();
    copy_out(pb, Pout + (size_t)t * PLANE, tid);
    __syncthreads();
  }
}

__global__ __launch_bounds__(256, 3) void k_l6(
    const char* __restrict__ Pin, const u16* __restrict__ W6,
    const float* __restrict__ bd3, const float* __restrict__ dvec,
    const float* __restrict__ xin, const float* __restrict__ Cptr,
    float* __restrict__ y_out, float* __restrict__ defen, float* __restrict__ msep) {
  extern __shared__ __align__(16) char lds[];
  char* pa = lds;
  char* pb = lds + PLANE;
  const int tid = threadIdx.x;
  const int lane = tid & 63;
  const int wid = tid >> 6, l15 = lane & 15, g = lane >> 4;
  for (int t = blockIdx.x; t < SPLIT_TILES; t += gridDim.x) {
    copy_in(Pin + (size_t)t * PLANE, pa, tid);
    __syncthreads();
    l6_body(pa, pb, W6, bd3, dvec, xin, Cptr, y_out, defen, msep + t,
            (size_t)t * ROWS, tid, wid, l15, g);
    __syncthreads();
  }
}

// ================= fallback: fused k_main (exact round-14 structure) =================
__global__ __launch_bounds__(256, 3) void k_main(
    const float* __restrict__ xin, const float* __restrict__ dvec,
    const float* __restrict__ be1, const float* __restrict__ be2, const float* __restrict__ be3,
    const float* __restrict__ bd1, const float* __restrict__ bd2, const float* __restrict__ bd3,
    const float* __restrict__ We3T, const float* __restrict__ Wd1,
    const u16* __restrict__ W1, const u16* __restrict__ W2,
    const u16* __restrict__ W5, const u16* __restrict__ W6,
    const float* __restrict__ Cptr,
    float* __restrict__ y_out, float* __restrict__ z_out,
    float* __restrict__ defen, float* __restrict__ msep) {
  extern __shared__ __align__(16) char lds[];
  char* pa = lds;
  char* pb = lds + PLANE;
  const int tid = threadIdx.x;
  const int lane = tid & 63;
  const int wid = tid >> 6, l15 = lane & 15, g = lane >> 4;
  const size_t row0 = (size_t)blockIdx.x * ROWS;

  stage_x(xin, row0, pa, tid);
  __syncthreads();
  for (int c = wid; c < 13; c += 4) {
    f32x4 acc[2][2] = {};
    gemm2<7>(pa, W1, 2 * c, l15, g, acc);
    epi2(acc, be1, 2 * c, pb, l15, g);
  }
  __syncthreads();
  for (int c = wid; c < 13; c += 4) {
    f32x4 acc[2][2] = {};
    gemm2<13>(pb, W2, 2 * c, l15, g, acc);
    epi2(acc, be2, 2 * c, pa, l15, g);
  }
  __syncthreads();
  l34_body(pa, pb, We3T, be3, Wd1, bd1, z_out, row0, tid, lane);
  __syncthreads();
  for (int c = wid; c < 13; c += 4) {
    f32x4 acc[2][2] = {};
    gemm2<13>(pb, W5, 2 * c, l15, g, acc);
    epi2(acc, bd2, 2 * c, pa, l15, g);
  }
  __syncthreads();
  l6_body(pa, pb, W6, bd3, dvec, xin, Cptr, y_out, defen, msep + blockIdx.x,
          row0, tid, wid, l15, g);
}

// ---------------- top-k stage A: 64 blocks, per-block top-20 of 2048 ----------------
__global__ void k_topk_a(const float* __restrict__ defen, float* __restrict__ cand) {
  __shared__ float vals[2048];
  __shared__ float wv[4];
  __shared__ int wi[4];
  const int tid = threadIdx.x;
  const int base = blockIdx.x * 2048;
  for (int i = tid; i < 2048; i += 256) vals[i] = defen[base + i];
  __syncthreads();
  for (int it = 0; it < 20; ++it) {
    float mv = -1e30f; int mi = 1 << 30;
    for (int i = tid; i < 2048; i += 256) {
      float v = vals[i];
      if (v > mv) { mv = v; mi = i; }
    }
#pragma unroll
    for (int off = 1; off < 64; off <<= 1) {
      float ov = __shfl_xor(mv, off); int oi = __shfl_xor(mi, off);
      if (ov > mv || (ov == mv && oi < mi)) { mv = ov; mi = oi; }
    }
    if ((tid & 63) == 0) { wv[tid >> 6] = mv; wi[tid >> 6] = mi; }
    __syncthreads();
    if (tid == 0) {
      float bv = wv[0]; int bi = wi[0];
      for (int q = 1; q < 4; ++q)
        if (wv[q] > bv || (wv[q] == bv && wi[q] < bi)) { bv = wv[q]; bi = wi[q]; }
      cand[blockIdx.x * 20 + it] = bv;
      vals[bi] = -1e30f;
    }
    __syncthreads();
  }
}

// ---------------- top-k stage B: final top-20 of 1280 + R_loss ----------------
__global__ void k_topk_b(const float* __restrict__ cand, const float* __restrict__ msep,
                         int nmse, float* __restrict__ rloss) {
  __shared__ float vals[1280];
  __shared__ float wv[4];
  __shared__ int wi[4];
  __shared__ float msum[4];
  const int tid = threadIdx.x;
  for (int i = tid; i < 1280; i += 256) vals[i] = cand[i];
  float ms = 0.f;
  for (int i = tid; i < nmse; i += 256) ms += msep[i];
#pragma unroll
  for (int off = 1; off < 64; off <<= 1) ms += __shfl_xor(ms, off);
  if ((tid & 63) == 0) msum[tid >> 6] = ms;
  __syncthreads();
  float sam = 0.f;
  for (int it = 0; it < 20; ++it) {
    float mv = -1e30f; int mi = 1 << 30;
    for (int i = tid; i < 1280; i += 256) {
      float v = vals[i];
      if (v > mv) { mv = v; mi = i; }
    }
#pragma unroll
    for (int off = 1; off < 64; off <<= 1) {
      float ov = __shfl_xor(mv, off); int oi = __shfl_xor(mi, off);
      if (ov > mv || (ov == mv && oi < mi)) { mv = ov; mi = oi; }
    }
    if ((tid & 63) == 0) { wv[tid >> 6] = mv; wi[tid >> 6] = mi; }
    __syncthreads();
    if (tid == 0) {
      float bv = wv[0]; int bi = wi[0];
      for (int q = 1; q < 4; ++q)
        if (wv[q] > bv || (wv[q] == bv && wi[q] < bi)) { bv = wv[q]; bi = wi[q]; }
      sam += bv;
      vals[bi] = -1e30f;
    }
    __syncthreads();
  }
  if (tid == 0) {
    float mse = (msum[0] + msum[1] + msum[2] + msum[3]) / 29360128.f;  // N*D
    rloss[0] = mse + 0.1f * sam;
  }
}

extern "C" void kernel_launch(void* const* d_in, const int* in_sizes, int n_in,
                              void* d_out, int out_size, void* d_ws, size_t ws_size,
                              hipStream_t stream) {
  const float* x    = (const float*)d_in[0];
  const float* dinp = (const float*)d_in[1];
  const float* We1  = (const float*)d_in[2];
  const float* be1  = (const float*)d_in[3];
  const float* We2  = (const float*)d_in[4];
  const float* be2  = (const float*)d_in[5];
  const float* We3  = (const float*)d_in[6];
  const float* be3  = (const float*)d_in[7];
  const float* Wd1  = (const float*)d_in[8];
  const float* bd1  = (const float*)d_in[9];
  const float* Wd2  = (const float*)d_in[10];
  const float* bd2  = (const float*)d_in[11];
  const float* Wd3  = (const float*)d_in[12];
  const float* bd3  = (const float*)d_in[13];

  float* y_out = (float*)d_out;
  float* z_out = y_out + (size_t)NROWS * DDIM;
  float* r_out = z_out + (size_t)NROWS * 4;

  char* ws = (char*)d_ws;
  u16* W1 = (u16*)(ws + OFF_W1);
  u16* W2 = (u16*)(ws + OFF_W2);
  u16* W5 = (u16*)(ws + OFF_W5);
  u16* W6 = (u16*)(ws + OFF_W6);
  float* Cf    = (float*)(ws + OFF_C);
  float* msep  = (float*)(ws + OFF_MSEP);
  float* defen = (float*)(ws + OFF_DEFEN);
  float* cand  = (float*)(ws + OFF_CAND);
  float* We3T  = (float*)(ws + OFF_WE3T);
  char* P0 = ws + OFF_P0;
  char* P1 = ws + OFF_P1;

  k_prep<<<dim3(256), dim3(256), 0, stream>>>(We1, We2, Wd2, Wd3, We3, dinp,
                                              W1, W2, W5, W6, We3T, Cf);
  if (ws_size >= WS_NEED) {
    // layer-major path: weights stay L2-hot (768 blocks vs 4096)
    k_l1<<<dim3(SPLIT_GRID), dim3(256), LDS_TOTAL, stream>>>(x, W1, be1, P0);
    k_gemm13<<<dim3(SPLIT_GRID), dim3(256), LDS_TOTAL, stream>>>(P0, W2, be2, P1);
    k_l34<<<dim3(SPLIT_GRID), dim3(256), LDS_TOTAL, stream>>>(P1, P0, We3T, be3, Wd1, bd1, z_out);
    k_gemm13<<<dim3(SPLIT_GRID), dim3(256), LDS_TOTAL, stream>>>(P0, W5, bd2, P1);
    k_l6<<<dim3(SPLIT_GRID), dim3(256), LDS_TOTAL, stream>>>(P1, W6, bd3, dinp, x, Cf,
                                                             y_out, defen, msep);
    k_topk_a<<<dim3(64), dim3(256), 0, stream>>>(defen, cand);
    k_topk_b<<<dim3(1), dim3(256), 0, stream>>>(cand, msep, SPLIT_TILES, r_out);
  } else {
    k_main<<<dim3(NTILES), dim3(256), LDS_TOTAL, stream>>>(x, dinp, be1, be2, be3,
                                                           bd1, bd2, bd3, We3T, Wd1,
                                                           W1, W2, W5, W6, Cf,
                                                           y_out, z_out, defen, msep);
    k_topk_a<<<dim3(64), dim3(256), 0, stream>>>(defen, cand);
    k_topk_b<<<dim3(1), dim3(256), 0, stream>>>(cand, msep, NTILES, r_out);
  }
}

// Round 18
// 490.858 us; speedup vs baseline: 1.3467x; 1.3467x over previous
//
#include <hip/hip_runtime.h>
#include <hip/hip_bf16.h>
#include <math.h>

typedef short bf16x8 __attribute__((ext_vector_type(8)));
typedef float f32x4 __attribute__((ext_vector_type(4)));
typedef unsigned int u32;
typedef unsigned short u16;

#define NROWS 131072
#define DDIM 224
#define HREAL 400
#define HP 416          // padded hidden dim (13*32)
#define ROWS 32         // rows per block
#define PROW 832        // bytes per plane row (416 * 2B = 52 units of 16B)
#define PLANE 26624     // one plane: [32][416] bf16
#define LDS_TOTAL 53248 // plane A + plane B (ping-pong); 3 blocks/CU

// ---- workspace layout (bytes); weights interleaved hi|lo per fragment ----
#define OFF_W1    0          // [26nb][7ks][4g][16l][8hi|8lo] u16 = 372736 B
#define OFF_W2    372736     // [26][13][4][16][16] = 692224 B
#define OFF_W5    1064960    // 692224 B
#define OFF_W6    1757184    // [14][13][4][16][16] = 372736 B
#define OFF_C     2129920    // f32 scalar ||d||
#define OFF_MSEP  2129936    // f32 [4096]
#define OFF_DEFEN 2146320    // f32 [131072]
#define OFF_CAND  2670608    // f32 [1280]
#define OFF_WE3T  2675728    // f32 [4][416] transposed+padded We3
// total 2682384 bytes

__device__ __forceinline__ u16 f2bf(float v) {
  union { float f; u32 u; } a; a.f = v;
  u32 u = a.u;
  u += 0x7fffu + ((u >> 16) & 1u);   // round-to-nearest-even
  return (u16)(u >> 16);
}
__device__ __forceinline__ float bf2f(u16 h) {
  union { u32 u; float f; } a; a.u = ((u32)h) << 16; return a.f;
}
// rotation swizzle: 16B unit u of row r lives at unit (u+r) mod 52.
__device__ __forceinline__ int rotu(int r, int u) {
  int s = u + r;
  if (s >= 52) s -= 52;
  if (s >= 52) s -= 52;
  return s;
}

// interleaved fragment packing: u16 index i -> (nb, ks, g, l15, half, e)
__device__ __forceinline__ void pack16(int i, int NKS, int KREAL, int NREAL, int NLD,
                                       const float* __restrict__ W,
                                       u16* __restrict__ Wo) {
  const int e = i & 7, half = (i >> 3) & 1;
  const int l15 = (i >> 4) & 15, g = (i >> 8) & 3;
  const int rest = i >> 10;
  const int ks = rest % NKS, nb = rest / NKS;
  const int n = nb * 16 + l15, k = ks * 32 + g * 8 + e;
  const float w = (n < NREAL && k < KREAL) ? W[k * NLD + n] : 0.f;
  const u16 h = f2bf(w);
  Wo[i] = half ? f2bf(w - bf2f(h)) : h;
}

__global__ void k_prep(const float* __restrict__ We1, const float* __restrict__ We2,
                       const float* __restrict__ Wd2, const float* __restrict__ Wd3,
                       const float* __restrict__ We3, const float* __restrict__ dvec,
                       u16* __restrict__ W1, u16* __restrict__ W2,
                       u16* __restrict__ W5, u16* __restrict__ W6,
                       float* __restrict__ We3T, float* __restrict__ Cout) {
  const int t = blockIdx.x * 256 + threadIdx.x;
  const int NT = gridDim.x * 256;
  for (int i = t; i < 26 * 7 * 1024;  i += NT) pack16(i, 7,  DDIM,  HREAL, HREAL, We1, W1);
  for (int i = t; i < 26 * 13 * 1024; i += NT) pack16(i, 13, HREAL, HREAL, HREAL, We2, W2);
  for (int i = t; i < 26 * 13 * 1024; i += NT) pack16(i, 13, HREAL, HREAL, HREAL, Wd2, W5);
  for (int i = t; i < 14 * 13 * 1024; i += NT) pack16(i, 13, HREAL, DDIM,  DDIM,  Wd3, W6);
  for (int i = t; i < 4 * 416; i += NT) {      // We3T[j][k] = We3[k][j], zero-padded
    const int j = i / 416, k = i - j * 416;
    We3T[i] = (k < HREAL) ? We3[k * 4 + j] : 0.f;
  }
  if (blockIdx.x == 0) {
    float s = 0.f;
    for (int i = threadIdx.x; i < DDIM; i += 256) { float v = dvec[i]; s += v * v; }
#pragma unroll
    for (int off = 1; off < 64; off <<= 1) s += __shfl_xor(s, off);
    __shared__ float cs[4];
    if ((threadIdx.x & 63) == 0) cs[threadIdx.x >> 6] = s;
    __syncthreads();
    if (threadIdx.x == 0) Cout[0] = sqrtf(cs[0] + cs[1] + cs[2] + cs[3]);
  }
}

// ------- GEMM chunk: 2 M-frags x 2 N-frags, 2-k-step-deep weight prefetch -------
// Slot index ks%3 is compile-time (loop fully unrolled) -> arrays stay in
// registers (rule #20). Prefetch issued ~2 k-steps (= full L2 latency) ahead.
template <int NKS>
__device__ __forceinline__ void gemm2(const char* ip, const u16* __restrict__ W,
                                      int nb0, int l15, int g, f32x4 (&acc)[2][2]) {
  const int lof = (g << 8) + (l15 << 4);
  const u16* w0 = W + ((((size_t)nb0 * NKS) << 10) + lof);
  const u16* w1 = W + ((((size_t)(nb0 + 1) * NKS) << 10) + lof);
  bf16x8 h0[3], l0[3], h1[3], l1[3];
  h0[0] = *(const bf16x8*)w0;          l0[0] = *(const bf16x8*)(w0 + 8);
  h1[0] = *(const bf16x8*)w1;          l1[0] = *(const bf16x8*)(w1 + 8);
  if (NKS > 1) {
    h0[1] = *(const bf16x8*)(w0 + 1024); l0[1] = *(const bf16x8*)(w0 + 1032);
    h1[1] = *(const bf16x8*)(w1 + 1024); l1[1] = *(const bf16x8*)(w1 + 1032);
  }
#pragma unroll
  for (int ks = 0; ks < NKS; ++ks) {
    const int cur = ks % 3;
    if (ks + 2 < NKS) {
      const int nxt = (ks + 2) % 3;
      const u16* p0 = w0 + (size_t)(ks + 2) * 1024;
      const u16* p1 = w1 + (size_t)(ks + 2) * 1024;
      h0[nxt] = *(const bf16x8*)p0; l0[nxt] = *(const bf16x8*)(p0 + 8);
      h1[nxt] = *(const bf16x8*)p1; l1[nxt] = *(const bf16x8*)(p1 + 8);
    }
    int s0 = ks * 4 + g + l15;
    if (s0 >= 52) s0 -= 52;
    int s1 = s0 + 16;
    if (s1 >= 52) s1 -= 52;
    const bf16x8 a0 = *(const bf16x8*)(ip + l15 * PROW + s0 * 16);
    const bf16x8 a1 = *(const bf16x8*)(ip + (l15 + 16) * PROW + s1 * 16);
    __builtin_amdgcn_s_setprio(1);
    acc[0][0] = __builtin_amdgcn_mfma_f32_16x16x32_bf16(a0, h0[cur], acc[0][0], 0, 0, 0);
    acc[0][0] = __builtin_amdgcn_mfma_f32_16x16x32_bf16(a0, l0[cur], acc[0][0], 0, 0, 0);
    acc[1][0] = __builtin_amdgcn_mfma_f32_16x16x32_bf16(a1, h0[cur], acc[1][0], 0, 0, 0);
    acc[1][0] = __builtin_amdgcn_mfma_f32_16x16x32_bf16(a1, l0[cur], acc[1][0], 0, 0, 0);
    acc[0][1] = __builtin_amdgcn_mfma_f32_16x16x32_bf16(a0, h1[cur], acc[0][1], 0, 0, 0);
    acc[0][1] = __builtin_amdgcn_mfma_f32_16x16x32_bf16(a0, l1[cur], acc[0][1], 0, 0, 0);
    acc[1][1] = __builtin_amdgcn_mfma_f32_16x16x32_bf16(a1, h1[cur], acc[1][1], 0, 0, 0);
    acc[1][1] = __builtin_amdgcn_mfma_f32_16x16x32_bf16(a1, l1[cur], acc[1][1], 0, 0, 0);
    __builtin_amdgcn_s_setprio(0);
  }
}

// ---------------- activation epilogue: bias + lrelu -> OUT plane ----------------
__device__ __forceinline__ void epi2(f32x4 (&acc)[2][2], const float* __restrict__ bias,
                                     int nb0, char* op, int l15, int g) {
#pragma unroll
  for (int nf = 0; nf < 2; ++nf) {
    const int col = (nb0 + nf) * 16 + l15;
    const float bv = (col < HREAL) ? bias[col] : 0.f;
    const int cu = col >> 3;
    const int crem = (col & 7) * 2;
#pragma unroll
    for (int mf = 0; mf < 2; ++mf) {
#pragma unroll
      for (int j = 0; j < 4; ++j) {
        const int row = mf * 16 + g * 4 + j;
        float v = acc[mf][nf][j] + bv;
        v = fmaxf(v, 0.1f * v);
        *(u16*)(op + row * PROW + rotu(row, cu) * 16 + crem) = f2bf(v);
      }
    }
  }
}

// ---------------- main fused kernel: 32 rows per block, 256 threads ----------------
// Ping-pong planes: each layer reads one plane, writes the other -> 1 barrier/layer.
__global__ __launch_bounds__(256, 3) void k_main(
    const float* __restrict__ xin, const float* __restrict__ dvec,
    const float* __restrict__ be1, const float* __restrict__ be2, const float* __restrict__ be3,
    const float* __restrict__ bd1, const float* __restrict__ bd2, const float* __restrict__ bd3,
    const float* __restrict__ We3T, const float* __restrict__ Wd1,
    const u16* __restrict__ W1, const u16* __restrict__ W2,
    const u16* __restrict__ W5, const u16* __restrict__ W6,
    const float* __restrict__ Cptr,
    float* __restrict__ y_out, float* __restrict__ z_out,
    float* __restrict__ defen, float* __restrict__ msep) {
  extern __shared__ __align__(16) char lds[];
  char* pa = lds;              // plane A
  char* pb = lds + PLANE;      // plane B

  const int tid = threadIdx.x;
  const int lane = tid & 63;
  const int wid = tid >> 6;       // 0..3
  const int l15 = lane & 15;
  const int g = lane >> 4;        // 0..3
  const size_t row0 = (size_t)blockIdx.x * ROWS;

  // ---- stage x -> plane A ----
#pragma unroll
  for (int i = 0; i < 7; ++i) {
    const int f = i * 256 + tid;                 // 32 rows * 56 float4 = 1792
    const int r = f / 56, c4 = f - r * 56;
    const float4 v = *(const float4*)(xin + (row0 + r) * DDIM + c4 * 4);
    const float vv[4] = {v.x, v.y, v.z, v.w};
    ushort4 hh;
    u16* hw = (u16*)&hh;
#pragma unroll
    for (int w = 0; w < 4; ++w) hw[w] = f2bf(vv[w]);
    *(ushort4*)(pa + r * PROW + rotu(r, c4 >> 1) * 16 + (c4 & 1) * 8) = hh;
  }
  __syncthreads();

  // ---- L1: x(A) -> h1(B); 13 chunks of 2 nb round-robin over 4 waves ----
  for (int c = wid; c < 13; c += 4) {
    f32x4 acc[2][2] = {};
    gemm2<7>(pa, W1, 2 * c, l15, g, acc);
    epi2(acc, be1, 2 * c, pb, l15, g);
  }
  __syncthreads();

  // ---- L2: h1(B) -> h2(A) ----
  for (int c = wid; c < 13; c += 4) {
    f32x4 acc[2][2] = {};
    gemm2<13>(pb, W2, 2 * c, l15, g, acc);
    epi2(acc, be2, 2 * c, pa, l15, g);
  }
  __syncthreads();

  // ---- L3: z = h2(A) @ We3 + be3 (Z=4), f32; 8 threads/row ----
  float zval;
  {
    const int r = tid >> 3;          // 0..31
    const int t8 = tid & 7;
    const int j = t8 & 3, half = t8 >> 2;
    const char* hb = pa + r * PROW;
    const float* wrow = We3T + j * 416;
    float s0 = 0.f, s1 = 0.f;
#pragma unroll 2
    for (int it = 0; it < 25; ++it) {
      const int k = half * 200 + it * 8;
      const bf16x8 h8 = *(const bf16x8*)(hb + rotu(r, half * 25 + it) * 16);
      const float4 w0 = *(const float4*)(wrow + k);
      const float4 w1 = *(const float4*)(wrow + k + 4);
      s0 = fmaf(bf2f((u16)h8[0]), w0.x, s0);
      s1 = fmaf(bf2f((u16)h8[1]), w0.y, s1);
      s0 = fmaf(bf2f((u16)h8[2]), w0.z, s0);
      s1 = fmaf(bf2f((u16)h8[3]), w0.w, s1);
      s0 = fmaf(bf2f((u16)h8[4]), w1.x, s0);
      s1 = fmaf(bf2f((u16)h8[5]), w1.y, s1);
      s0 = fmaf(bf2f((u16)h8[6]), w1.z, s0);
      s1 = fmaf(bf2f((u16)h8[7]), w1.w, s1);
    }
    float s = s0 + s1;
    s += __shfl_xor(s, 4);           // combine K-halves, preserve j
    s += be3[j];
    zval = s;
    if (half == 0) z_out[(row0 + r) * 4 + j] = s;
  }
  // no barrier: L3 reads A (own rows), L4 writes B.

  // ---- L4: g1 = lrelu(z @ Wd1 + bd1) -> plane B ----
  {
    const int r = tid >> 3, q = tid & 7;
    float z[4];
#pragma unroll
    for (int jj = 0; jj < 4; ++jj) z[jj] = __shfl(zval, (lane & ~7) + jj);
#pragma unroll 2
    for (int u = 0; u < 13; ++u) {
      const int c4 = q * 13 + u;                 // 104 groups of 4 cols = 416
      ushort4 hh;
      u16* hw = (u16*)&hh;
      if (c4 < 100) {                            // cols < 400
        const float4 w0 = *(const float4*)(Wd1 + 0 * HREAL + c4 * 4);
        const float4 w1 = *(const float4*)(Wd1 + 1 * HREAL + c4 * 4);
        const float4 w2 = *(const float4*)(Wd1 + 2 * HREAL + c4 * 4);
        const float4 w3 = *(const float4*)(Wd1 + 3 * HREAL + c4 * 4);
        const float4 bb = *(const float4*)(bd1 + c4 * 4);
        const float ww[4][4] = {{w0.x, w1.x, w2.x, w3.x}, {w0.y, w1.y, w2.y, w3.y},
                                {w0.z, w1.z, w2.z, w3.z}, {w0.w, w1.w, w2.w, w3.w}};
        const float bbv[4] = {bb.x, bb.y, bb.z, bb.w};
#pragma unroll
        for (int w = 0; w < 4; ++w) {
          float v = fmaf(z[0], ww[w][0], fmaf(z[1], ww[w][1],
                    fmaf(z[2], ww[w][2], fmaf(z[3], ww[w][3], bbv[w]))));
          v = fmaxf(v, 0.1f * v);
          hw[w] = f2bf(v);
        }
      } else {
        hw[0] = hw[1] = hw[2] = hw[3] = 0;
      }
      *(ushort4*)(pb + r * PROW + rotu(r, c4 >> 1) * 16 + (c4 & 1) * 8) = hh;
    }
  }
  __syncthreads();

  // ---- L5: g2 = lrelu(g1(B) @ Wd2 + bd2) -> plane A ----
  for (int c = wid; c < 13; c += 4) {
    f32x4 acc[2][2] = {};
    gemm2<13>(pb, W5, 2 * c, l15, g, acc);
    epi2(acc, bd2, 2 * c, pa, l15, g);
  }
  __syncthreads();                 // B now free (red overlay), A holds g2

  // ---- L6: y = tanh(g2(A) @ Wd3 + bd3) + fused reductions ----
  // 7 chunks of 2 nb over 4 waves: w0:{0,4} w1:{1,5} w2:{2,6} w3:{3}
  {
    float pA[2][4] = {}, pB[2][4] = {}, pM[2][4] = {};
    for (int c = wid; c < 7; c += 4) {
      const int nb0 = 2 * c;
      f32x4 acc[2][2] = {};
      gemm2<13>(pa, W6, nb0, l15, g, acc);
#pragma unroll
      for (int mf = 0; mf < 2; ++mf) {
#pragma unroll
        for (int j = 0; j < 4; ++j) {
          const size_t grow = row0 + mf * 16 + g * 4 + j;
#pragma unroll
          for (int nf = 0; nf < 2; ++nf) {
            const int col = (nb0 + nf) * 16 + l15;
            const float v = acc[mf][nf][j] + bd3[col];
            const float e = __expf(2.f * v);
            const float y = 1.f - 2.f * __builtin_amdgcn_rcpf(e + 1.f);
            y_out[grow * DDIM + col] = y;
            pA[mf][j] = fmaf(y, dvec[col], pA[mf][j]);
            pB[mf][j] = fmaf(y, y, pB[mf][j]);
            const float df = y - xin[grow * DDIM + col];
            pM[mf][j] = fmaf(df, df, pM[mf][j]);
          }
        }
      }
    }
    float* red = (float*)pb;       // [32 rows][4 waves][4]
#pragma unroll
    for (int mf = 0; mf < 2; ++mf) {
#pragma unroll
      for (int j = 0; j < 4; ++j) {
        float a = pA[mf][j], b = pB[mf][j], m = pM[mf][j];
#pragma unroll
        for (int off = 1; off < 16; off <<= 1) {
          a += __shfl_xor(a, off);
          b += __shfl_xor(b, off);
          m += __shfl_xor(m, off);
        }
        if (l15 == 0) {
          const int lrow = mf * 16 + g * 4 + j;
          red[(lrow * 4 + wid) * 4 + 0] = a;
          red[(lrow * 4 + wid) * 4 + 1] = b;
          red[(lrow * 4 + wid) * 4 + 2] = m;
        }
      }
    }
  }
  __syncthreads();

  if (tid < 32) {
    const float Cn = Cptr[0];
    const float* red = (const float*)pb;
    float A = 0.f, B2 = 0.f, M = 0.f;
#pragma unroll
    for (int w = 0; w < 4; ++w) {
      A  += red[(tid * 4 + w) * 4 + 0];
      B2 += red[(tid * 4 + w) * 4 + 1];
      M  += red[(tid * 4 + w) * 4 + 2];
    }
    defen[row0 + tid] = A / (sqrtf(B2) * Cn + 1e-5f);
#pragma unroll
    for (int off = 1; off < 32; off <<= 1) M += __shfl_xor(M, off);
    if (tid == 0) msep[blockIdx.x] = M;
  }
}

// ---------------- top-k stage A: 64 blocks, per-block top-20 of 2048 ----------------
__global__ void k_topk_a(const float* __restrict__ defen, float* __restrict__ cand) {
  __shared__ float vals[2048];
  __shared__ float wv[4];
  __shared__ int wi[4];
  const int tid = threadIdx.x;
  const int base = blockIdx.x * 2048;
  for (int i = tid; i < 2048; i += 256) vals[i] = defen[base + i];
  __syncthreads();
  for (int it = 0; it < 20; ++it) {
    float mv = -1e30f; int mi = 1 << 30;
    for (int i = tid; i < 2048; i += 256) {
      float v = vals[i];
      if (v > mv) { mv = v; mi = i; }
    }
#pragma unroll
    for (int off = 1; off < 64; off <<= 1) {
      float ov = __shfl_xor(mv, off); int oi = __shfl_xor(mi, off);
      if (ov > mv || (ov == mv && oi < mi)) { mv = ov; mi = oi; }
    }
    if ((tid & 63) == 0) { wv[tid >> 6] = mv; wi[tid >> 6] = mi; }
    __syncthreads();
    if (tid == 0) {
      float bv = wv[0]; int bi = wi[0];
      for (int q = 1; q < 4; ++q)
        if (wv[q] > bv || (wv[q] == bv && wi[q] < bi)) { bv = wv[q]; bi = wi[q]; }
      cand[blockIdx.x * 20 + it] = bv;
      vals[bi] = -1e30f;
    }
    __syncthreads();
  }
}

// ---------------- top-k stage B: final top-20 of 1280 + R_loss ----------------
__global__ void k_topk_b(const float* __restrict__ cand, const float* __restrict__ msep,
                         float* __restrict__ rloss) {
  __shared__ float vals[1280];
  __shared__ float wv[4];
  __shared__ int wi[4];
  __shared__ float msum[4];
  const int tid = threadIdx.x;
  for (int i = tid; i < 1280; i += 256) vals[i] = cand[i];
  float ms = 0.f;
  for (int i = tid; i < 4096; i += 256) ms += msep[i];
#pragma unroll
  for (int off = 1; off < 64; off <<= 1) ms += __shfl_xor(ms, off);
  if ((tid & 63) == 0) msum[tid >> 6] = ms;
  __syncthreads();
  float sam = 0.f;
  for (int it = 0; it < 20; ++it) {
    float mv = -1e30f; int mi = 1 << 30;
    for (int i = tid; i < 1280; i += 256) {
      float v = vals[i];
      if (v > mv) { mv = v; mi = i; }
    }
#pragma unroll
    for (int off = 1; off < 64; off <<= 1) {
      float ov = __shfl_xor(mv, off); int oi = __shfl_xor(mi, off);
      if (ov > mv || (ov == mv && oi < mi)) { mv = ov; mi = oi; }
    }
    if ((tid & 63) == 0) { wv[tid >> 6] = mv; wi[tid >> 6] = mi; }
    __syncthreads();
    if (tid == 0) {
      float bv = wv[0]; int bi = wi[0];
      for (int q = 1; q < 4; ++q)
        if (wv[q] > bv || (wv[q] == bv && wi[q] < bi)) { bv = wv[q]; bi = wi[q]; }
      sam += bv;
      vals[bi] = -1e30f;
    }
    __syncthreads();
  }
  if (tid == 0) {
    float mse = (msum[0] + msum[1] + msum[2] + msum[3]) / 29360128.f;  // N*D
    rloss[0] = mse + 0.1f * sam;
  }
}

extern "C" void kernel_launch(void* const* d_in, const int* in_sizes, int n_in,
                              void* d_out, int out_size, void* d_ws, size_t ws_size,
                              hipStream_t stream) {
  const float* x    = (const float*)d_in[0];
  const float* dinp = (const float*)d_in[1];
  const float* We1  = (const float*)d_in[2];
  const float* be1  = (const float*)d_in[3];
  const float* We2  = (const float*)d_in[4];
  const float* be2  = (const float*)d_in[5];
  const float* We3  = (const float*)d_in[6];
  const float* be3  = (const float*)d_in[7];
  const float* Wd1  = (const float*)d_in[8];
  const float* bd1  = (const float*)d_in[9];
  const float* Wd2  = (const float*)d_in[10];
  const float* bd2  = (const float*)d_in[11];
  const float* Wd3  = (const float*)d_in[12];
  const float* bd3  = (const float*)d_in[13];

  float* y_out = (float*)d_out;
  float* z_out = y_out + (size_t)NROWS * DDIM;
  float* r_out = z_out + (size_t)NROWS * 4;

  char* ws = (char*)d_ws;
  u16* W1 = (u16*)(ws + OFF_W1);
  u16* W2 = (u16*)(ws + OFF_W2);
  u16* W5 = (u16*)(ws + OFF_W5);
  u16* W6 = (u16*)(ws + OFF_W6);
  float* Cf    = (float*)(ws + OFF_C);
  float* msep  = (float*)(ws + OFF_MSEP);
  float* defen = (float*)(ws + OFF_DEFEN);
  float* cand  = (float*)(ws + OFF_CAND);
  float* We3T  = (float*)(ws + OFF_WE3T);

  (void)hipFuncSetAttribute((const void*)k_main, hipFuncAttributeMaxDynamicSharedMemorySize, LDS_TOTAL);

  k_prep<<<dim3(256), dim3(256), 0, stream>>>(We1, We2, Wd2, Wd3, We3, dinp,
                                              W1, W2, W5, W6, We3T, Cf);
  k_main<<<dim3(4096), dim3(256), LDS_TOTAL, stream>>>(x, dinp, be1, be2, be3, bd1, bd2, bd3,
                                                       We3T, Wd1, W1, W2, W5, W6,
                                                       Cf, y_out, z_out, defen, msep);
  k_topk_a<<<dim3(64), dim3(256), 0, stream>>>(defen, cand);
  k_topk_b<<<dim3(1), dim3(256), 0, stream>>>(cand, msep, r_out);
}

// Round 19
// 394.980 us; speedup vs baseline: 1.6736x; 1.2427x over previous
//
#include <hip/hip_runtime.h>
#include <hip/hip_bf16.h>
#include <math.h>

typedef _Float16 f16x8 __attribute__((ext_vector_type(8)));
typedef float f32x4 __attribute__((ext_vector_type(4)));
typedef unsigned int u32;
typedef unsigned short u16;

#define NROWS 131072
#define DDIM 224
#define HREAL 400
#define HP 416          // padded hidden dim (13*32)
#define ROWS 32         // rows per block
#define PROW 832        // bytes per plane row (416 * 2B = 52 units of 16B)
#define PLANE 26624     // one plane: [32][416] f16
#define LDS_TOTAL 53248 // plane A + plane B (ping-pong); 3 blocks/CU

// ---- workspace layout (bytes); weights single-f16 fragment-linear ----
#define OFF_W1    0          // [26nb][7ks][4g][16l][8] u16 = 186368 B
#define OFF_W2    186368     // [26][13][4][16][8] = 346112 B
#define OFF_W5    532480     // 346112 B
#define OFF_W6    878592     // [14][13][4][16][8] = 186368 B
#define OFF_C     1064960    // f32 scalar ||d||
#define OFF_MSEP  1064976    // f32 [4096]
#define OFF_DEFEN 1081360    // f32 [131072]
#define OFF_CAND  1605648    // f32 [1280]
#define OFF_WE3T  1610768    // f32 [4][416] transposed+padded We3
// total 1617424 bytes

__device__ __forceinline__ u16 f2h(float v) {
  union { _Float16 h; u16 u; } c;
  c.h = (_Float16)v;
  return c.u;
}
__device__ __forceinline__ float h2f(u16 b) {
  union { u16 u; _Float16 h; } c;
  c.u = b;
  return (float)c.h;
}
// rotation swizzle: 16B unit u of row r lives at unit (u+r) mod 52.
__device__ __forceinline__ int rotu(int r, int u) {
  int s = u + r;
  if (s >= 52) s -= 52;
  if (s >= 52) s -= 52;
  return s;
}

// single-f16 fragment packing: u16 index i -> (nb, ks, g, l15, e)
__device__ __forceinline__ void pack8(int i, int NKS, int KREAL, int NREAL, int NLD,
                                      const float* __restrict__ W,
                                      u16* __restrict__ Wo) {
  const int e = i & 7, l15 = (i >> 3) & 15, g = (i >> 7) & 3;
  const int rest = i >> 9;
  const int ks = rest % NKS, nb = rest / NKS;
  const int n = nb * 16 + l15, k = ks * 32 + g * 8 + e;
  const float w = (n < NREAL && k < KREAL) ? W[k * NLD + n] : 0.f;
  Wo[i] = f2h(w);
}

__global__ void k_prep(const float* __restrict__ We1, const float* __restrict__ We2,
                       const float* __restrict__ Wd2, const float* __restrict__ Wd3,
                       const float* __restrict__ We3, const float* __restrict__ dvec,
                       u16* __restrict__ W1, u16* __restrict__ W2,
                       u16* __restrict__ W5, u16* __restrict__ W6,
                       float* __restrict__ We3T, float* __restrict__ Cout) {
  const int t = blockIdx.x * 256 + threadIdx.x;
  const int NT = gridDim.x * 256;
  for (int i = t; i < 26 * 7 * 512;  i += NT) pack8(i, 7,  DDIM,  HREAL, HREAL, We1, W1);
  for (int i = t; i < 26 * 13 * 512; i += NT) pack8(i, 13, HREAL, HREAL, HREAL, We2, W2);
  for (int i = t; i < 26 * 13 * 512; i += NT) pack8(i, 13, HREAL, HREAL, HREAL, Wd2, W5);
  for (int i = t; i < 14 * 13 * 512; i += NT) pack8(i, 13, HREAL, DDIM,  DDIM,  Wd3, W6);
  for (int i = t; i < 4 * 416; i += NT) {      // We3T[j][k] = We3[k][j], zero-padded
    const int j = i / 416, k = i - j * 416;
    We3T[i] = (k < HREAL) ? We3[k * 4 + j] : 0.f;
  }
  if (blockIdx.x == 0) {
    float s = 0.f;
    for (int i = threadIdx.x; i < DDIM; i += 256) { float v = dvec[i]; s += v * v; }
#pragma unroll
    for (int off = 1; off < 64; off <<= 1) s += __shfl_xor(s, off);
    __shared__ float cs[4];
    if ((threadIdx.x & 63) == 0) cs[threadIdx.x >> 6] = s;
    __syncthreads();
    if (threadIdx.x == 0) Cout[0] = sqrtf(cs[0] + cs[1] + cs[2] + cs[3]);
  }
}

// ------- GEMM chunk: 2 M-frags x 2 N-frags, f16 single-W, 2-deep prefetch -------
// Slot index ks%3 is compile-time (loop fully unrolled) -> registers (rule #20).
template <int NKS>
__device__ __forceinline__ void gemm2(const char* ip, const u16* __restrict__ W,
                                      int nb0, int l15, int g, f32x4 (&acc)[2][2]) {
  const int lof = (g << 7) + (l15 << 3);
  const u16* w0 = W + ((((size_t)nb0 * NKS) << 9) + lof);
  const u16* w1 = W + ((((size_t)(nb0 + 1) * NKS) << 9) + lof);
  f16x8 b0[3], b1[3];
  b0[0] = *(const f16x8*)w0;
  b1[0] = *(const f16x8*)w1;
  if (NKS > 1) {
    b0[1] = *(const f16x8*)(w0 + 512);
    b1[1] = *(const f16x8*)(w1 + 512);
  }
#pragma unroll
  for (int ks = 0; ks < NKS; ++ks) {
    const int cur = ks % 3;
    if (ks + 2 < NKS) {
      const int nxt = (ks + 2) % 3;
      b0[nxt] = *(const f16x8*)(w0 + (size_t)(ks + 2) * 512);
      b1[nxt] = *(const f16x8*)(w1 + (size_t)(ks + 2) * 512);
    }
    int s0 = ks * 4 + g + l15;
    if (s0 >= 52) s0 -= 52;
    int s1 = s0 + 16;
    if (s1 >= 52) s1 -= 52;
    const f16x8 a0 = *(const f16x8*)(ip + l15 * PROW + s0 * 16);
    const f16x8 a1 = *(const f16x8*)(ip + (l15 + 16) * PROW + s1 * 16);
    __builtin_amdgcn_s_setprio(1);
    acc[0][0] = __builtin_amdgcn_mfma_f32_16x16x32_f16(a0, b0[cur], acc[0][0], 0, 0, 0);
    acc[1][0] = __builtin_amdgcn_mfma_f32_16x16x32_f16(a1, b0[cur], acc[1][0], 0, 0, 0);
    acc[0][1] = __builtin_amdgcn_mfma_f32_16x16x32_f16(a0, b1[cur], acc[0][1], 0, 0, 0);
    acc[1][1] = __builtin_amdgcn_mfma_f32_16x16x32_f16(a1, b1[cur], acc[1][1], 0, 0, 0);
    __builtin_amdgcn_s_setprio(0);
  }
}

// ---------------- activation epilogue: bias + lrelu -> OUT plane (f16) ----------------
__device__ __forceinline__ void epi2(f32x4 (&acc)[2][2], const float* __restrict__ bias,
                                     int nb0, char* op, int l15, int g) {
#pragma unroll
  for (int nf = 0; nf < 2; ++nf) {
    const int col = (nb0 + nf) * 16 + l15;
    const float bv = (col < HREAL) ? bias[col] : 0.f;
    const int cu = col >> 3;
    const int crem = (col & 7) * 2;
#pragma unroll
    for (int mf = 0; mf < 2; ++mf) {
#pragma unroll
      for (int j = 0; j < 4; ++j) {
        const int row = mf * 16 + g * 4 + j;
        float v = acc[mf][nf][j] + bv;
        v = fmaxf(v, 0.1f * v);
        *(u16*)(op + row * PROW + rotu(row, cu) * 16 + crem) = f2h(v);
      }
    }
  }
}

// ---------------- main fused kernel: 32 rows per block, 256 threads ----------------
// Ping-pong planes: each layer reads one plane, writes the other -> 1 barrier/layer.
__global__ __launch_bounds__(256, 3) void k_main(
    const float* __restrict__ xin, const float* __restrict__ dvec,
    const float* __restrict__ be1, const float* __restrict__ be2, const float* __restrict__ be3,
    const float* __restrict__ bd1, const float* __restrict__ bd2, const float* __restrict__ bd3,
    const float* __restrict__ We3T, const float* __restrict__ Wd1,
    const u16* __restrict__ W1, const u16* __restrict__ W2,
    const u16* __restrict__ W5, const u16* __restrict__ W6,
    const float* __restrict__ Cptr,
    float* __restrict__ y_out, float* __restrict__ z_out,
    float* __restrict__ defen, float* __restrict__ msep) {
  extern __shared__ __align__(16) char lds[];
  char* pa = lds;              // plane A
  char* pb = lds + PLANE;      // plane B

  const int tid = threadIdx.x;
  const int lane = tid & 63;
  const int wid = tid >> 6;       // 0..3
  const int l15 = lane & 15;
  const int g = lane >> 4;        // 0..3
  const size_t row0 = (size_t)blockIdx.x * ROWS;

  // ---- stage x -> plane A (f16) ----
#pragma unroll
  for (int i = 0; i < 7; ++i) {
    const int f = i * 256 + tid;                 // 32 rows * 56 float4 = 1792
    const int r = f / 56, c4 = f - r * 56;
    const float4 v = *(const float4*)(xin + (row0 + r) * DDIM + c4 * 4);
    const float vv[4] = {v.x, v.y, v.z, v.w};
    ushort4 hh;
    u16* hw = (u16*)&hh;
#pragma unroll
    for (int w = 0; w < 4; ++w) hw[w] = f2h(vv[w]);
    *(ushort4*)(pa + r * PROW + rotu(r, c4 >> 1) * 16 + (c4 & 1) * 8) = hh;
  }
  __syncthreads();

  // ---- L1: x(A) -> h1(B); 13 chunks of 2 nb round-robin over 4 waves ----
  for (int c = wid; c < 13; c += 4) {
    f32x4 acc[2][2] = {};
    gemm2<7>(pa, W1, 2 * c, l15, g, acc);
    epi2(acc, be1, 2 * c, pb, l15, g);
  }
  __syncthreads();

  // ---- L2: h1(B) -> h2(A) ----
  for (int c = wid; c < 13; c += 4) {
    f32x4 acc[2][2] = {};
    gemm2<13>(pb, W2, 2 * c, l15, g, acc);
    epi2(acc, be2, 2 * c, pa, l15, g);
  }
  __syncthreads();

  // ---- L3: z = h2(A) @ We3 + be3 (Z=4), f32; 8 threads/row ----
  float zval;
  {
    const int r = tid >> 3;          // 0..31
    const int t8 = tid & 7;
    const int j = t8 & 3, half = t8 >> 2;
    const char* hb = pa + r * PROW;
    const float* wrow = We3T + j * 416;
    float s0 = 0.f, s1 = 0.f;
#pragma unroll 2
    for (int it = 0; it < 25; ++it) {
      const int k = half * 200 + it * 8;
      const f16x8 h8 = *(const f16x8*)(hb + rotu(r, half * 25 + it) * 16);
      const float4 w0 = *(const float4*)(wrow + k);
      const float4 w1 = *(const float4*)(wrow + k + 4);
      s0 = fmaf((float)h8[0], w0.x, s0);
      s1 = fmaf((float)h8[1], w0.y, s1);
      s0 = fmaf((float)h8[2], w0.z, s0);
      s1 = fmaf((float)h8[3], w0.w, s1);
      s0 = fmaf((float)h8[4], w1.x, s0);
      s1 = fmaf((float)h8[5], w1.y, s1);
      s0 = fmaf((float)h8[6], w1.z, s0);
      s1 = fmaf((float)h8[7], w1.w, s1);
    }
    float s = s0 + s1;
    s += __shfl_xor(s, 4);           // combine K-halves, preserve j
    s += be3[j];
    zval = s;
    if (half == 0) z_out[(row0 + r) * 4 + j] = s;
  }
  // no barrier: L3 reads A (own rows), L4 writes B.

  // ---- L4: g1 = lrelu(z @ Wd1 + bd1) -> plane B (f16) ----
  {
    const int r = tid >> 3, q = tid & 7;
    float z[4];
#pragma unroll
    for (int jj = 0; jj < 4; ++jj) z[jj] = __shfl(zval, (lane & ~7) + jj);
#pragma unroll 2
    for (int u = 0; u < 13; ++u) {
      const int c4 = q * 13 + u;                 // 104 groups of 4 cols = 416
      ushort4 hh;
      u16* hw = (u16*)&hh;
      if (c4 < 100) {                            // cols < 400
        const float4 w0 = *(const float4*)(Wd1 + 0 * HREAL + c4 * 4);
        const float4 w1 = *(const float4*)(Wd1 + 1 * HREAL + c4 * 4);
        const float4 w2 = *(const float4*)(Wd1 + 2 * HREAL + c4 * 4);
        const float4 w3 = *(const float4*)(Wd1 + 3 * HREAL + c4 * 4);
        const float4 bb = *(const float4*)(bd1 + c4 * 4);
        const float ww[4][4] = {{w0.x, w1.x, w2.x, w3.x}, {w0.y, w1.y, w2.y, w3.y},
                                {w0.z, w1.z, w2.z, w3.z}, {w0.w, w1.w, w2.w, w3.w}};
        const float bbv[4] = {bb.x, bb.y, bb.z, bb.w};
#pragma unroll
        for (int w = 0; w < 4; ++w) {
          float v = fmaf(z[0], ww[w][0], fmaf(z[1], ww[w][1],
                    fmaf(z[2], ww[w][2], fmaf(z[3], ww[w][3], bbv[w]))));
          v = fmaxf(v, 0.1f * v);
          hw[w] = f2h(v);
        }
      } else {
        hw[0] = hw[1] = hw[2] = hw[3] = 0;
      }
      *(ushort4*)(pb + r * PROW + rotu(r, c4 >> 1) * 16 + (c4 & 1) * 8) = hh;
    }
  }
  __syncthreads();

  // ---- L5: g2 = lrelu(g1(B) @ Wd2 + bd2) -> plane A ----
  for (int c = wid; c < 13; c += 4) {
    f32x4 acc[2][2] = {};
    gemm2<13>(pb, W5, 2 * c, l15, g, acc);
    epi2(acc, bd2, 2 * c, pa, l15, g);
  }
  __syncthreads();                 // B now free (red overlay), A holds g2

  // ---- L6: y = tanh(g2(A) @ Wd3 + bd3) + fused reductions ----
  // 7 chunks of 2 nb over 4 waves: w0:{0,4} w1:{1,5} w2:{2,6} w3:{3}
  {
    float pA[2][4] = {}, pB[2][4] = {}, pM[2][4] = {};
    for (int c = wid; c < 7; c += 4) {
      const int nb0 = 2 * c;
      f32x4 acc[2][2] = {};
      gemm2<13>(pa, W6, nb0, l15, g, acc);
#pragma unroll
      for (int mf = 0; mf < 2; ++mf) {
#pragma unroll
        for (int j = 0; j < 4; ++j) {
          const size_t grow = row0 + mf * 16 + g * 4 + j;
#pragma unroll
          for (int nf = 0; nf < 2; ++nf) {
            const int col = (nb0 + nf) * 16 + l15;
            const float v = acc[mf][nf][j] + bd3[col];
            const float e = __expf(2.f * v);
            const float y = 1.f - 2.f * __builtin_amdgcn_rcpf(e + 1.f);
            y_out[grow * DDIM + col] = y;
            pA[mf][j] = fmaf(y, dvec[col], pA[mf][j]);
            pB[mf][j] = fmaf(y, y, pB[mf][j]);
            const float df = y - xin[grow * DDIM + col];
            pM[mf][j] = fmaf(df, df, pM[mf][j]);
          }
        }
      }
    }
    float* red = (float*)pb;       // [32 rows][4 waves][4]
#pragma unroll
    for (int mf = 0; mf < 2; ++mf) {
#pragma unroll
      for (int j = 0; j < 4; ++j) {
        float a = pA[mf][j], b = pB[mf][j], m = pM[mf][j];
#pragma unroll
        for (int off = 1; off < 16; off <<= 1) {
          a += __shfl_xor(a, off);
          b += __shfl_xor(b, off);
          m += __shfl_xor(m, off);
        }
        if (l15 == 0) {
          const int lrow = mf * 16 + g * 4 + j;
          red[(lrow * 4 + wid) * 4 + 0] = a;
          red[(lrow * 4 + wid) * 4 + 1] = b;
          red[(lrow * 4 + wid) * 4 + 2] = m;
        }
      }
    }
  }
  __syncthreads();

  if (tid < 32) {
    const float Cn = Cptr[0];
    const float* red = (const float*)pb;
    float A = 0.f, B2 = 0.f, M = 0.f;
#pragma unroll
    for (int w = 0; w < 4; ++w) {
      A  += red[(tid * 4 + w) * 4 + 0];
      B2 += red[(tid * 4 + w) * 4 + 1];
      M  += red[(tid * 4 + w) * 4 + 2];
    }
    defen[row0 + tid] = A / (sqrtf(B2) * Cn + 1e-5f);
#pragma unroll
    for (int off = 1; off < 32; off <<= 1) M += __shfl_xor(M, off);
    if (tid == 0) msep[blockIdx.x] = M;
  }
}

// ---------------- top-k stage A: 64 blocks, per-block top-20 of 2048 ----------------
__global__ void k_topk_a(const float* __restrict__ defen, float* __restrict__ cand) {
  __shared__ float vals[2048];
  __shared__ float wv[4];
  __shared__ int wi[4];
  const int tid = threadIdx.x;
  const int base = blockIdx.x * 2048;
  for (int i = tid; i < 2048; i += 256) vals[i] = defen[base + i];
  __syncthreads();
  for (int it = 0; it < 20; ++it) {
    float mv = -1e30f; int mi = 1 << 30;
    for (int i = tid; i < 2048; i += 256) {
      float v = vals[i];
      if (v > mv) { mv = v; mi = i; }
    }
#pragma unroll
    for (int off = 1; off < 64; off <<= 1) {
      float ov = __shfl_xor(mv, off); int oi = __shfl_xor(mi, off);
      if (ov > mv || (ov == mv && oi < mi)) { mv = ov; mi = oi; }
    }
    if ((tid & 63) == 0) { wv[tid >> 6] = mv; wi[tid >> 6] = mi; }
    __syncthreads();
    if (tid == 0) {
      float bv = wv[0]; int bi = wi[0];
      for (int q = 1; q < 4; ++q)
        if (wv[q] > bv || (wv[q] == bv && wi[q] < bi)) { bv = wv[q]; bi = wi[q]; }
      cand[blockIdx.x * 20 + it] = bv;
      vals[bi] = -1e30f;
    }
    __syncthreads();
  }
}

// ---------------- top-k stage B: final top-20 of 1280 + R_loss ----------------
__global__ void k_topk_b(const float* __restrict__ cand, const float* __restrict__ msep,
                         float* __restrict__ rloss) {
  __shared__ float vals[1280];
  __shared__ float wv[4];
  __shared__ int wi[4];
  __shared__ float msum[4];
  const int tid = threadIdx.x;
  for (int i = tid; i < 1280; i += 256) vals[i] = cand[i];
  float ms = 0.f;
  for (int i = tid; i < 4096; i += 256) ms += msep[i];
#pragma unroll
  for (int off = 1; off < 64; off <<= 1) ms += __shfl_xor(ms, off);
  if ((tid & 63) == 0) msum[tid >> 6] = ms;
  __syncthreads();
  float sam = 0.f;
  for (int it = 0; it < 20; ++it) {
    float mv = -1e30f; int mi = 1 << 30;
    for (int i = tid; i < 1280; i += 256) {
      float v = vals[i];
      if (v > mv) { mv = v; mi = i; }
    }
#pragma unroll
    for (int off = 1; off < 64; off <<= 1) {
      float ov = __shfl_xor(mv, off); int oi = __shfl_xor(mi, off);
      if (ov > mv || (ov == mv && oi < mi)) { mv = ov; mi = oi; }
    }
    if ((tid & 63) == 0) { wv[tid >> 6] = mv; wi[tid >> 6] = mi; }
    __syncthreads();
    if (tid == 0) {
      float bv = wv[0]; int bi = wi[0];
      for (int q = 1; q < 4; ++q)
        if (wv[q] > bv || (wv[q] == bv && wi[q] < bi)) { bv = wv[q]; bi = wi[q]; }
      sam += bv;
      vals[bi] = -1e30f;
    }
    __syncthreads();
  }
  if (tid == 0) {
    float mse = (msum[0] + msum[1] + msum[2] + msum[3]) / 29360128.f;  // N*D
    rloss[0] = mse + 0.1f * sam;
  }
}

extern "C" void kernel_launch(void* const* d_in, const int* in_sizes, int n_in,
                              void* d_out, int out_size, void* d_ws, size_t ws_size,
                              hipStream_t stream) {
  const float* x    = (const float*)d_in[0];
  const float* dinp = (const float*)d_in[1];
  const float* We1  = (const float*)d_in[2];
  const float* be1  = (const float*)d_in[3];
  const float* We2  = (const float*)d_in[4];
  const float* be2  = (const float*)d_in[5];
  const float* We3  = (const float*)d_in[6];
  const float* be3  = (const float*)d_in[7];
  const float* Wd1  = (const float*)d_in[8];
  const float* bd1  = (const float*)d_in[9];
  const float* Wd2  = (const float*)d_in[10];
  const float* bd2  = (const float*)d_in[11];
  const float* Wd3  = (const float*)d_in[12];
  const float* bd3  = (const float*)d_in[13];

  float* y_out = (float*)d_out;
  float* z_out = y_out + (size_t)NROWS * DDIM;
  float* r_out = z_out + (size_t)NROWS * 4;

  char* ws = (char*)d_ws;
  u16* W1 = (u16*)(ws + OFF_W1);
  u16* W2 = (u16*)(ws + OFF_W2);
  u16* W5 = (u16*)(ws + OFF_W5);
  u16* W6 = (u16*)(ws + OFF_W6);
  float* Cf    = (float*)(ws + OFF_C);
  float* msep  = (float*)(ws + OFF_MSEP);
  float* defen = (float*)(ws + OFF_DEFEN);
  float* cand  = (float*)(ws + OFF_CAND);
  float* We3T  = (float*)(ws + OFF_WE3T);

  (void)hipFuncSetAttribute((const void*)k_main, hipFuncAttributeMaxDynamicSharedMemorySize, LDS_TOTAL);

  k_prep<<<dim3(256), dim3(256), 0, stream>>>(We1, We2, Wd2, Wd3, We3, dinp,
                                              W1, W2, W5, W6, We3T, Cf);
  k_main<<<dim3(4096), dim3(256), LDS_TOTAL, stream>>>(x, dinp, be1, be2, be3, bd1, bd2, bd3,
                                                       We3T, Wd1, W1, W2, W5, W6,
                                                       Cf, y_out, z_out, defen, msep);
  k_topk_a<<<dim3(64), dim3(256), 0, stream>>>(defen, cand);
  k_topk_b<<<dim3(1), dim3(256), 0, stream>>>(cand, msep, r_out);
}

// Round 20
// 316.908 us; speedup vs baseline: 2.0858x; 1.2464x over previous
//
#include <hip/hip_runtime.h>
#include <hip/hip_bf16.h>
#include <math.h>

typedef _Float16 f16x8 __attribute__((ext_vector_type(8)));
typedef float f32x4 __attribute__((ext_vector_type(4)));
typedef unsigned int u32;
typedef unsigned short u16;

#define NROWS 131072
#define DDIM 224
#define HREAL 400
#define HP 416          // padded hidden dim (13*32)
#define ROWS 32         // rows per block
#define PROW 832        // bytes per plane row (416 * 2B = 52 units of 16B)
#define PLANE 26624     // one plane: [32][416] f16
#define LDS_TOTAL 53248 // plane A + plane B (ping-pong); 3 blocks/CU

// ---- workspace layout (bytes); weights single-f16 fragment-linear ----
#define OFF_W1    0          // [26nb][7ks][4g][16l][8] u16 = 186368 B
#define OFF_W2    186368     // [26][13][4][16][8] = 346112 B
#define OFF_W5    532480     // 346112 B
#define OFF_W6    878592     // [14][13][4][16][8] = 186368 B
#define OFF_W3    1064960    // [1][13][4][16][8] = 13312 B  (We3 as B-frag, N=16 cols<4 real)
#define OFF_W4    1078272    // [26][1][4][16][8] = 26624 B  (Wd1 as B-frag, K=32 k<4 real)
#define OFF_C     1104896    // f32 scalar ||d||
#define OFF_MSEP  1104912    // f32 [4096]
#define OFF_DEFEN 1121296    // f32 [131072]
#define OFF_CAND  1645584    // f32 [1280]
// total 1650704 bytes

__device__ __forceinline__ u16 f2h(float v) {
  union { _Float16 h; u16 u; } c;
  c.h = (_Float16)v;
  return c.u;
}
// rotation swizzle: 16B unit u of row r lives at unit (u+r) mod 52.
__device__ __forceinline__ int rotu(int r, int u) {
  int s = u + r;
  if (s >= 52) s -= 52;
  if (s >= 52) s -= 52;
  return s;
}

// single-f16 fragment packing: u16 index i -> (nb, ks, g, l15, e)
__device__ __forceinline__ void pack8(int i, int NKS, int KREAL, int NREAL, int NLD,
                                      const float* __restrict__ W,
                                      u16* __restrict__ Wo) {
  const int e = i & 7, l15 = (i >> 3) & 15, g = (i >> 7) & 3;
  const int rest = i >> 9;
  const int ks = rest % NKS, nb = rest / NKS;
  const int n = nb * 16 + l15, k = ks * 32 + g * 8 + e;
  const float w = (n < NREAL && k < KREAL) ? W[k * NLD + n] : 0.f;
  Wo[i] = f2h(w);
}

__global__ void k_prep(const float* __restrict__ We1, const float* __restrict__ We2,
                       const float* __restrict__ Wd2, const float* __restrict__ Wd3,
                       const float* __restrict__ We3, const float* __restrict__ Wd1,
                       const float* __restrict__ dvec,
                       u16* __restrict__ W1, u16* __restrict__ W2,
                       u16* __restrict__ W5, u16* __restrict__ W6,
                       u16* __restrict__ W3, u16* __restrict__ W4,
                       float* __restrict__ Cout) {
  const int t = blockIdx.x * 256 + threadIdx.x;
  const int NT = gridDim.x * 256;
  for (int i = t; i < 26 * 7 * 512;  i += NT) pack8(i, 7,  DDIM,  HREAL, HREAL, We1, W1);
  for (int i = t; i < 26 * 13 * 512; i += NT) pack8(i, 13, HREAL, HREAL, HREAL, We2, W2);
  for (int i = t; i < 26 * 13 * 512; i += NT) pack8(i, 13, HREAL, HREAL, HREAL, Wd2, W5);
  for (int i = t; i < 14 * 13 * 512; i += NT) pack8(i, 13, HREAL, DDIM,  DDIM,  Wd3, W6);
  for (int i = t; i < 1 * 13 * 512;  i += NT) pack8(i, 13, HREAL, 4,     4,     We3, W3);
  for (int i = t; i < 26 * 1 * 512;  i += NT) pack8(i, 1,  4,     HREAL, HREAL, Wd1, W4);
  if (blockIdx.x == 0) {
    float s = 0.f;
    for (int i = threadIdx.x; i < DDIM; i += 256) { float v = dvec[i]; s += v * v; }
#pragma unroll
    for (int off = 1; off < 64; off <<= 1) s += __shfl_xor(s, off);
    __shared__ float cs[4];
    if ((threadIdx.x & 63) == 0) cs[threadIdx.x >> 6] = s;
    __syncthreads();
    if (threadIdx.x == 0) Cout[0] = sqrtf(cs[0] + cs[1] + cs[2] + cs[3]);
  }
}

// ------- GEMM chunk: 2 M-frags x NFW N-frags, f16 single-W, 2-deep prefetch -------
// Slot index ks%3 is compile-time (loop fully unrolled) -> registers (rule #20).
template <int NKS, int NFW>
__device__ __forceinline__ void gemmN(const char* ip, const u16* __restrict__ W,
                                      int nb0, int l15, int g, f32x4 (&acc)[2][NFW]) {
  const int lof = (g << 7) + (l15 << 3);
  const u16* wp[NFW];
#pragma unroll
  for (int nf = 0; nf < NFW; ++nf)
    wp[nf] = W + ((((size_t)(nb0 + nf) * NKS) << 9) + lof);
  f16x8 b[NFW][3];
#pragma unroll
  for (int nf = 0; nf < NFW; ++nf) b[nf][0] = *(const f16x8*)wp[nf];
  if (NKS > 1) {
#pragma unroll
    for (int nf = 0; nf < NFW; ++nf) b[nf][1] = *(const f16x8*)(wp[nf] + 512);
  }
#pragma unroll
  for (int ks = 0; ks < NKS; ++ks) {
    const int cur = ks % 3;
    if (ks + 2 < NKS) {
      const int nxt = (ks + 2) % 3;
#pragma unroll
      for (int nf = 0; nf < NFW; ++nf)
        b[nf][nxt] = *(const f16x8*)(wp[nf] + (size_t)(ks + 2) * 512);
    }
    int s0 = ks * 4 + g + l15;
    if (s0 >= 52) s0 -= 52;
    int s1 = s0 + 16;
    if (s1 >= 52) s1 -= 52;
    const f16x8 a0 = *(const f16x8*)(ip + l15 * PROW + s0 * 16);
    const f16x8 a1 = *(const f16x8*)(ip + (l15 + 16) * PROW + s1 * 16);
    __builtin_amdgcn_s_setprio(1);
#pragma unroll
    for (int nf = 0; nf < NFW; ++nf) {
      acc[0][nf] = __builtin_amdgcn_mfma_f32_16x16x32_f16(a0, b[nf][cur], acc[0][nf], 0, 0, 0);
      acc[1][nf] = __builtin_amdgcn_mfma_f32_16x16x32_f16(a1, b[nf][cur], acc[1][nf], 0, 0, 0);
    }
    __builtin_amdgcn_s_setprio(0);
  }
}

// ---------------- activation epilogue: bias + lrelu -> OUT plane (f16) ----------------
__device__ __forceinline__ void epi2(f32x4 (&acc)[2][2], const float* __restrict__ bias,
                                     int nb0, char* op, int l15, int g) {
#pragma unroll
  for (int nf = 0; nf < 2; ++nf) {
    const int col = (nb0 + nf) * 16 + l15;
    const float bv = (col < HREAL) ? bias[col] : 0.f;
    const int cu = col >> 3;
    const int crem = (col & 7) * 2;
#pragma unroll
    for (int mf = 0; mf < 2; ++mf) {
#pragma unroll
      for (int j = 0; j < 4; ++j) {
        const int row = mf * 16 + g * 4 + j;
        float v = acc[mf][nf][j] + bv;
        v = fmaxf(v, 0.1f * v);
        *(u16*)(op + row * PROW + rotu(row, cu) * 16 + crem) = f2h(v);
      }
    }
  }
}

// ---------------- main fused kernel: 32 rows per block, 256 threads ----------------
// Ping-pong planes; L3/L4 are MFMA too (z as a K=32 A-fragment in the plane).
__global__ __launch_bounds__(256, 3) void k_main(
    const float* __restrict__ xin, const float* __restrict__ dvec,
    const float* __restrict__ be1, const float* __restrict__ be2, const float* __restrict__ be3,
    const float* __restrict__ bd1, const float* __restrict__ bd2, const float* __restrict__ bd3,
    const u16* __restrict__ W1, const u16* __restrict__ W2,
    const u16* __restrict__ W5, const u16* __restrict__ W6,
    const u16* __restrict__ W3, const u16* __restrict__ W4,
    const float* __restrict__ Cptr,
    float* __restrict__ y_out, float* __restrict__ z_out,
    float* __restrict__ defen, float* __restrict__ msep) {
  extern __shared__ __align__(16) char lds[];
  char* pa = lds;              // plane A
  char* pb = lds + PLANE;      // plane B

  const int tid = threadIdx.x;
  const int lane = tid & 63;
  const int wid = tid >> 6;       // 0..3
  const int l15 = lane & 15;
  const int g = lane >> 4;        // 0..3
  const size_t row0 = (size_t)blockIdx.x * ROWS;

  // ---- stage x -> plane A (f16) ----
#pragma unroll
  for (int i = 0; i < 7; ++i) {
    const int f = i * 256 + tid;                 // 32 rows * 56 float4 = 1792
    const int r = f / 56, c4 = f - r * 56;
    const float4 v = *(const float4*)(xin + (row0 + r) * DDIM + c4 * 4);
    const float vv[4] = {v.x, v.y, v.z, v.w};
    ushort4 hh;
    u16* hw = (u16*)&hh;
#pragma unroll
    for (int w = 0; w < 4; ++w) hw[w] = f2h(vv[w]);
    *(ushort4*)(pa + r * PROW + rotu(r, c4 >> 1) * 16 + (c4 & 1) * 8) = hh;
  }
  __syncthreads();

  // ---- L1: x(A) -> h1(B); 13 chunks of 2 nb round-robin over 4 waves ----
  for (int c = wid; c < 13; c += 4) {
    f32x4 acc[2][2] = {};
    gemmN<7, 2>(pa, W1, 2 * c, l15, g, acc);
    epi2(acc, be1, 2 * c, pb, l15, g);
  }
  __syncthreads();

  // ---- L2: h1(B) -> h2(A) ----
  for (int c = wid; c < 13; c += 4) {
    f32x4 acc[2][2] = {};
    gemmN<13, 2>(pb, W2, 2 * c, l15, g, acc);
    epi2(acc, be2, 2 * c, pa, l15, g);
  }
  __syncthreads();

  // ---- L3 (MFMA): z = h2(A) @ We3 + be3; wave 0 only ----
  // Output z scattered into plane B as a ready A-fragment (K=32, k<4 real).
  if (wid == 0) {
    f32x4 acc3[2][1] = {};
    gemmN<13, 1>(pa, W3, 0, l15, g, acc3);
    float zv[2][4];
#pragma unroll
    for (int mf = 0; mf < 2; ++mf) {
#pragma unroll
      for (int j = 0; j < 4; ++j) {
        const float s = acc3[mf][0][j] + ((l15 < 4) ? be3[l15] : 0.f);
        zv[mf][j] = s;
        if (l15 < 4) z_out[(row0 + mf * 16 + g * 4 + j) * 4 + l15] = s;
      }
    }
    // pack z (k=0..3) into unit 0; zero units 1..3 (k=8..31) of each row
#pragma unroll
    for (int mf = 0; mf < 2; ++mf) {
#pragma unroll
      for (int j = 0; j < 4; ++j) {
        const float z0 = __shfl(zv[mf][j], (lane & ~15) + 0);
        const float z1 = __shfl(zv[mf][j], (lane & ~15) + 1);
        const float z2 = __shfl(zv[mf][j], (lane & ~15) + 2);
        const float z3 = __shfl(zv[mf][j], (lane & ~15) + 3);
        if (l15 < 4) {
          const int r = mf * 16 + g * 4 + j;
          uint4 zq = {0u, 0u, 0u, 0u};
          if (l15 == 0) {
            zq.x = (u32)f2h(z0) | ((u32)f2h(z1) << 16);
            zq.y = (u32)f2h(z2) | ((u32)f2h(z3) << 16);
          }
          *(uint4*)(pb + r * PROW + rotu(r, l15) * 16) = zq;
        }
      }
    }
  }
  __syncthreads();

  // ---- L4 (MFMA): g1 = lrelu(z(B) @ Wd1 + bd1) -> plane A ----
  for (int c = wid; c < 13; c += 4) {
    f32x4 acc[2][2] = {};
    gemmN<1, 2>(pb, W4, 2 * c, l15, g, acc);
    epi2(acc, bd1, 2 * c, pa, l15, g);
  }
  __syncthreads();

  // ---- L5: g2 = lrelu(g1(A) @ Wd2 + bd2) -> plane B ----
  for (int c = wid; c < 13; c += 4) {
    f32x4 acc[2][2] = {};
    gemmN<13, 2>(pa, W5, 2 * c, l15, g, acc);
    epi2(acc, bd2, 2 * c, pb, l15, g);
  }
  __syncthreads();                 // A now free (red overlay), B holds g2

  // ---- L6: y = tanh(g2(B) @ Wd3 + bd3) + fused reductions ----
  // 7 chunks of 2 nb over 4 waves: w0:{0,4} w1:{1,5} w2:{2,6} w3:{3}
  {
    float pA[2][4] = {}, pB[2][4] = {}, pM[2][4] = {};
    for (int c = wid; c < 7; c += 4) {
      const int nb0 = 2 * c;
      f32x4 acc[2][2] = {};
      gemmN<13, 2>(pb, W6, nb0, l15, g, acc);
#pragma unroll
      for (int mf = 0; mf < 2; ++mf) {
#pragma unroll
        for (int j = 0; j < 4; ++j) {
          const size_t grow = row0 + mf * 16 + g * 4 + j;
#pragma unroll
          for (int nf = 0; nf < 2; ++nf) {
            const int col = (nb0 + nf) * 16 + l15;
            const float v = acc[mf][nf][j] + bd3[col];
            const float e = __expf(2.f * v);
            const float y = 1.f - 2.f * __builtin_amdgcn_rcpf(e + 1.f);
            y_out[grow * DDIM + col] = y;
            pA[mf][j] = fmaf(y, dvec[col], pA[mf][j]);
            pB[mf][j] = fmaf(y, y, pB[mf][j]);
            const float df = y - xin[grow * DDIM + col];
            pM[mf][j] = fmaf(df, df, pM[mf][j]);
          }
        }
      }
    }
    float* red = (float*)pa;       // [32 rows][4 waves][4]
#pragma unroll
    for (int mf = 0; mf < 2; ++mf) {
#pragma unroll
      for (int j = 0; j < 4; ++j) {
        float a = pA[mf][j], b = pB[mf][j], m = pM[mf][j];
#pragma unroll
        for (int off = 1; off < 16; off <<= 1) {
          a += __shfl_xor(a, off);
          b += __shfl_xor(b, off);
          m += __shfl_xor(m, off);
        }
        if (l15 == 0) {
          const int lrow = mf * 16 + g * 4 + j;
          red[(lrow * 4 + wid) * 4 + 0] = a;
          red[(lrow * 4 + wid) * 4 + 1] = b;
          red[(lrow * 4 + wid) * 4 + 2] = m;
        }
      }
    }
  }
  __syncthreads();

  if (tid < 32) {
    const float Cn = Cptr[0];
    const float* red = (const float*)pa;
    float A = 0.f, B2 = 0.f, M = 0.f;
#pragma unroll
    for (int w = 0; w < 4; ++w) {
      A  += red[(tid * 4 + w) * 4 + 0];
      B2 += red[(tid * 4 + w) * 4 + 1];
      M  += red[(tid * 4 + w) * 4 + 2];
    }
    defen[row0 + tid] = A / (sqrtf(B2) * Cn + 1e-5f);
#pragma unroll
    for (int off = 1; off < 32; off <<= 1) M += __shfl_xor(M, off);
    if (tid == 0) msep[blockIdx.x] = M;
  }
}

// ---------------- top-k stage A: 64 blocks, per-block top-20 of 2048 ----------------
__global__ void k_topk_a(const float* __restrict__ defen, float* __restrict__ cand) {
  __shared__ float vals[2048];
  __shared__ float wv[4];
  __shared__ int wi[4];
  const int tid = threadIdx.x;
  const int base = blockIdx.x * 2048;
  for (int i = tid; i < 2048; i += 256) vals[i] = defen[base + i];
  __syncthreads();
  for (int it = 0; it < 20; ++it) {
    float mv = -1e30f; int mi = 1 << 30;
    for (int i = tid; i < 2048; i += 256) {
      float v = vals[i];
      if (v > mv) { mv = v; mi = i; }
    }
#pragma unroll
    for (int off = 1; off < 64; off <<= 1) {
      float ov = __shfl_xor(mv, off); int oi = __shfl_xor(mi, off);
      if (ov > mv || (ov == mv && oi < mi)) { mv = ov; mi = oi; }
    }
    if ((tid & 63) == 0) { wv[tid >> 6] = mv; wi[tid >> 6] = mi; }
    __syncthreads();
    if (tid == 0) {
      float bv = wv[0]; int bi = wi[0];
      for (int q = 1; q < 4; ++q)
        if (wv[q] > bv || (wv[q] == bv && wi[q] < bi)) { bv = wv[q]; bi = wi[q]; }
      cand[blockIdx.x * 20 + it] = bv;
      vals[bi] = -1e30f;
    }
    __syncthreads();
  }
}

// ---------------- top-k stage B: final top-20 of 1280 + R_loss ----------------
__global__ void k_topk_b(const float* __restrict__ cand, const float* __restrict__ msep,
                         float* __restrict__ rloss) {
  __shared__ float vals[1280];
  __shared__ float wv[4];
  __shared__ int wi[4];
  __shared__ float msum[4];
  const int tid = threadIdx.x;
  for (int i = tid; i < 1280; i += 256) vals[i] = cand[i];
  float ms = 0.f;
  for (int i = tid; i < 4096; i += 256) ms += msep[i];
#pragma unroll
  for (int off = 1; off < 64; off <<= 1) ms += __shfl_xor(ms, off);
  if ((tid & 63) == 0) msum[tid >> 6] = ms;
  __syncthreads();
  float sam = 0.f;
  for (int it = 0; it < 20; ++it) {
    float mv = -1e30f; int mi = 1 << 30;
    for (int i = tid; i < 1280; i += 256) {
      float v = vals[i];
      if (v > mv) { mv = v; mi = i; }
    }
#pragma unroll
    for (int off = 1; off < 64; off <<= 1) {
      float ov = __shfl_xor(mv, off); int oi = __shfl_xor(mi, off);
      if (ov > mv || (ov == mv && oi < mi)) { mv = ov; mi = oi; }
    }
    if ((tid & 63) == 0) { wv[tid >> 6] = mv; wi[tid >> 6] = mi; }
    __syncthreads();
    if (tid == 0) {
      float bv = wv[0]; int bi = wi[0];
      for (int q = 1; q < 4; ++q)
        if (wv[q] > bv || (wv[q] == bv && wi[q] < bi)) { bv = wv[q]; bi = wi[q]; }
      sam += bv;
      vals[bi] = -1e30f;
    }
    __syncthreads();
  }
  if (tid == 0) {
    float mse = (msum[0] + msum[1] + msum[2] + msum[3]) / 29360128.f;  // N*D
    rloss[0] = mse + 0.1f * sam;
  }
}

extern "C" void kernel_launch(void* const* d_in, const int* in_sizes, int n_in,
                              void* d_out, int out_size, void* d_ws, size_t ws_size,
                              hipStream_t stream) {
  const float* x    = (const float*)d_in[0];
  const float* dinp = (const float*)d_in[1];
  const float* We1  = (const float*)d_in[2];
  const float* be1  = (const float*)d_in[3];
  const float* We2  = (const float*)d_in[4];
  const float* be2  = (const float*)d_in[5];
  const float* We3  = (const float*)d_in[6];
  const float* be3  = (const float*)d_in[7];
  const float* Wd1  = (const float*)d_in[8];
  const float* bd1  = (const float*)d_in[9];
  const float* Wd2  = (const float*)d_in[10];
  const float* bd2  = (const float*)d_in[11];
  const float* Wd3  = (const float*)d_in[12];
  const float* bd3  = (const float*)d_in[13];

  float* y_out = (float*)d_out;
  float* z_out = y_out + (size_t)NROWS * DDIM;
  float* r_out = z_out + (size_t)NROWS * 4;

  char* ws = (char*)d_ws;
  u16* W1 = (u16*)(ws + OFF_W1);
  u16* W2 = (u16*)(ws + OFF_W2);
  u16* W5 = (u16*)(ws + OFF_W5);
  u16* W6 = (u16*)(ws + OFF_W6);
  u16* W3 = (u16*)(ws + OFF_W3);
  u16* W4 = (u16*)(ws + OFF_W4);
  float* Cf    = (float*)(ws + OFF_C);
  float* msep  = (float*)(ws + OFF_MSEP);
  float* defen = (float*)(ws + OFF_DEFEN);
  float* cand  = (float*)(ws + OFF_CAND);

  (void)hipFuncSetAttribute((const void*)k_main, hipFuncAttributeMaxDynamicSharedMemorySize, LDS_TOTAL);

  k_prep<<<dim3(256), dim3(256), 0, stream>>>(We1, We2, Wd2, Wd3, We3, Wd1, dinp,
                                              W1, W2, W5, W6, W3, W4, Cf);
  k_main<<<dim3(4096), dim3(256), LDS_TOTAL, stream>>>(x, dinp, be1, be2, be3, bd1, bd2, bd3,
                                                       W1, W2, W5, W6, W3, W4,
                                                       Cf, y_out, z_out, defen, msep);
  k_topk_a<<<dim3(64), dim3(256), 0, stream>>>(defen, cand);
  k_topk_b<<<dim3(1), dim3(256), 0, stream>>>(cand, msep, r_out);
}